// Round 8
// baseline (250.272 us; speedup 1.0000x reference)
//
#include <hip/hip_runtime.h>
#include <hip/hip_bf16.h>

#define S_  384
#define H_  256
#define NH_ 8
#define DH_ 32
#define B_  4
#define PADK 385

typedef _Float16 f16x8 __attribute__((ext_vector_type(8)));
typedef _Float16 f16x4 __attribute__((ext_vector_type(4)));
typedef float    f32x4 __attribute__((ext_vector_type(4)));

// ---------------- Kernel P: fused QKV projections ----------------
// z==0 -> Qb (f32), z==1 -> Kf (f16), z==2 -> Vb (f32)
__global__ __launch_bounds__(256) void proj_kernel(
    const float* __restrict__ query, const float* __restrict__ key, const float* __restrict__ value,
    const float* __restrict__ Wq, const float* __restrict__ bq,
    const float* __restrict__ Wk, const float* __restrict__ bk,
    const float* __restrict__ Wv, const float* __restrict__ bv,
    float* __restrict__ Qb, _Float16* __restrict__ Kf, float* __restrict__ Vb)
{
    __shared__ __align__(16) float As[32][36];
    __shared__ __align__(16) float Bs[32][68];
    const int t = threadIdx.x;
    const int m0g = blockIdx.x * 32;
    const int n0g = blockIdx.y * 64;
    const int z = blockIdx.z;
    const float* X    = (z == 0) ? query : (z == 1 ? key : value);
    const float* W    = (z == 0) ? Wq    : (z == 1 ? Wk  : Wv);
    const float* bias = (z == 0) ? bq    : (z == 1 ? bk  : bv);

    const int tn = (t & 15) * 4;
    const int tm = (t >> 4) * 2;
    float acc0[4] = {0.f,0.f,0.f,0.f};
    float acc1[4] = {0.f,0.f,0.f,0.f};

    const int ar = t >> 3, ac4 = (t & 7) * 4;
    const int brr = t >> 4, bc4 = (t & 15) * 4;

    for (int kt = 0; kt < 8; ++kt) {
        const int k0 = kt * 32;
        float4 av  = *(const float4*)&X[(size_t)(m0g + ar) * H_ + k0 + ac4];
        float4 bv0 = *(const float4*)&W[(size_t)(k0 + brr)      * H_ + n0g + bc4];
        float4 bv1 = *(const float4*)&W[(size_t)(k0 + brr + 16) * H_ + n0g + bc4];
        *(float4*)&As[ar][ac4] = av;
        *(float4*)&Bs[brr][bc4] = bv0;
        *(float4*)&Bs[brr + 16][bc4] = bv1;
        __syncthreads();
        #pragma unroll
        for (int c = 0; c < 32; ++c) {
            const float a0 = As[tm][c], a1 = As[tm + 1][c];
            const float4 b4 = *(const float4*)&Bs[c][tn];
            acc0[0] += a0 * b4.x; acc0[1] += a0 * b4.y; acc0[2] += a0 * b4.z; acc0[3] += a0 * b4.w;
            acc1[0] += a1 * b4.x; acc1[1] += a1 * b4.y; acc1[2] += a1 * b4.z; acc1[3] += a1 * b4.w;
        }
        __syncthreads();
    }
    const float4 bi = *(const float4*)&bias[n0g + tn];
    float4 o0 = make_float4(acc0[0] + bi.x, acc0[1] + bi.y, acc0[2] + bi.z, acc0[3] + bi.w);
    float4 o1 = make_float4(acc1[0] + bi.x, acc1[1] + bi.y, acc1[2] + bi.z, acc1[3] + bi.w);
    if (z == 1) {
        f16x4 h0 = { (_Float16)o0.x, (_Float16)o0.y, (_Float16)o0.z, (_Float16)o0.w };
        f16x4 h1 = { (_Float16)o1.x, (_Float16)o1.y, (_Float16)o1.z, (_Float16)o1.w };
        *(f16x4*)&Kf[(size_t)(m0g + tm)     * H_ + n0g + tn] = h0;
        *(f16x4*)&Kf[(size_t)(m0g + tm + 1) * H_ + n0g + tn] = h1;
    } else {
        float* Out = (z == 0) ? Qb : Vb;
        *(float4*)&Out[(size_t)(m0g + tm)     * H_ + n0g + tn] = o0;
        *(float4*)&Out[(size_t)(m0g + tm + 1) * H_ + n0g + tn] = o1;
    }
}

// ---------------- Kernel QW: Af[rowQ][h][e] = f16(sum_d Q[rowQ,h*32+d] * Wr[e,h*32+d]) ----
__global__ __launch_bounds__(256) void qw_kernel(
    const float* __restrict__ Qb, const float* __restrict__ Wr,
    _Float16* __restrict__ Af)
{
    __shared__ __align__(16) float Qs[16][36];
    const int t = threadIdx.x;                // e index
    const int m0 = blockIdx.x * 16;
    const int h = blockIdx.y;

    float4 wr4[8];
    #pragma unroll
    for (int j = 0; j < 8; ++j)
        wr4[j] = *(const float4*)&Wr[(size_t)t * H_ + h * DH_ + j * 4];

    if (t < 128) {
        const int r = t >> 3, d4 = (t & 7) * 4;
        *(float4*)&Qs[r][d4] = *(const float4*)&Qb[(size_t)(m0 + r) * H_ + h * DH_ + d4];
    }
    __syncthreads();

    #pragma unroll 4
    for (int r = 0; r < 16; ++r) {
        float acc = 0.f;
        #pragma unroll
        for (int j = 0; j < 8; ++j) {
            const float4 qv = *(const float4*)&Qs[r][j * 4];
            acc += qv.x * wr4[j].x + qv.y * wr4[j].y + qv.z * wr4[j].z + qv.w * wr4[j].w;
        }
        Af[((size_t)(m0 + r) * NH_ + h) * 256 + t] = (_Float16)acc;
    }
}

// ---------------- Kernel B: MFMA scores (8-key tiles, high occupancy) + softmax + PV ----
// One WG per (b,q); 4 waves; wave w owns 8-key tiles kt = w, w+4, ...
// LDS: sc 12.3KB + stg 16KB = 28.3KB -> 5 blocks/CU (20 waves/CU).
// Per tile: stage 8 rpe rows f32->f16 into swizzled wave-private LDS, then
// 8 rpe-MFMA (LDS) + 8 K-MFMA (qfrag select). C cols 8-15 (garbage keys) discarded.
__global__ __launch_bounds__(256, 5) void attn_kernel(
    const float* __restrict__ rpe, const _Float16* __restrict__ Af,
    const _Float16* __restrict__ Kf, const float* __restrict__ Qb,
    const float* __restrict__ Vb,
    const int* __restrict__ seq_len, const int* __restrict__ lex_num,
    float* __restrict__ out)
{
    __shared__ float sc[NH_ * PADK];
    __shared__ __align__(16) _Float16 stg[4][8][256];
    const int blk = blockIdx.x;
    const int b = blk / S_;
    const int q = blk - b * S_;
    const int t = threadIdx.x;
    const int lane = t & 63;
    const int wave = t >> 6;
    int limit = seq_len[b] + lex_num[b];
    limit = limit < 0 ? 0 : (limit > S_ ? S_ : limit);
    const size_t rowQ = (size_t)(b * S_ + q);

    if (limit == 0) {
        float acc = 0.f;
        const float* vb = Vb + (size_t)b * S_ * H_ + t;
        for (int k = 0; k < S_; ++k) acc += vb[(size_t)k * H_];
        out[rowQ * H_ + t] = acc * (1.0f / S_);
        return;
    }

    const int r = lane & 15;     // fragment row (key within 16-wide C; valid keys r<8)
    const int g = lane >> 4;     // contraction k-group
    const int rc = r & 7;        // staged LDS row / A row

    // qW-part A fragments: 8 steps x f16x8 (32 VGPR)
    f16x8 afrag[8];
    {
        const _Float16* Arow = Af + (rowQ * NH_ + rc) * 256 + g * 8;
        #pragma unroll
        for (int j = 0; j < 8; ++j)
            afrag[j] = *(const f16x8*)(Arow + j * 32);
    }
    // Q fragment for the A_C part; used only in K-step j==r (r<8)
    f16x8 qfrag;
    {
        const float* qsrc = Qb + rowQ * H_ + rc * 32 + g * 8;
        const float4 q0 = *(const float4*)qsrc;
        const float4 q1 = *(const float4*)(qsrc + 4);
        qfrag[0] = (_Float16)q0.x; qfrag[1] = (_Float16)q0.y;
        qfrag[2] = (_Float16)q0.z; qfrag[3] = (_Float16)q0.w;
        qfrag[4] = (_Float16)q1.x; qfrag[5] = (_Float16)q1.y;
        qfrag[6] = (_Float16)q1.z; qfrag[7] = (_Float16)q1.w;
    }
    const f16x8 zfrag = {};

    char* myl = (char*)&stg[wave][0][0];
    const int swz = rc << 4;
    const float* rpe_base = rpe + rowQ * (size_t)S_ * H_;
    const int ntiles = (limit + 7) >> 3;

    for (int kt = wave; kt < ntiles; kt += 4) {
        const int k0 = kt * 8;
        const float* gsrc = rpe_base + (size_t)k0 * H_;
        // ---- stage 8 rows (f32 -> f16, swizzled) ----
        float4 v[8];
        #pragma unroll
        for (int rr = 0; rr < 8; ++rr)
            v[rr] = *(const float4*)&gsrc[(size_t)rr * H_ + lane * 4];
        #pragma unroll
        for (int rr = 0; rr < 8; ++rr) {
            f16x4 hv = { (_Float16)v[rr].x, (_Float16)v[rr].y,
                         (_Float16)v[rr].z, (_Float16)v[rr].w };
            *(f16x4*)(myl + rr * 512 + ((lane * 8) ^ (rr << 4))) = hv;
        }
        // ---- MFMA: 8 rpe steps (LDS) + 8 K steps ----
        f32x4 acc = {};
        #pragma unroll
        for (int j = 0; j < 8; ++j) {
            f16x8 bf = *(const f16x8*)(myl + rc * 512 + ((j * 64 + g * 16) ^ swz));
            acc = __builtin_amdgcn_mfma_f32_16x16x32_f16(afrag[j], bf, acc, 0, 0, 0);
        }
        const _Float16* krow = Kf + ((size_t)(b * S_ + k0 + r)) * H_ + g * 8;
        #pragma unroll
        for (int j = 0; j < 8; ++j) {
            const f16x8 kf = *(const f16x8*)(krow + j * 32);
            const f16x8 af = (r == j) ? qfrag : zfrag;
            acc = __builtin_amdgcn_mfma_f32_16x16x32_f16(af, kf, acc, 0, 0, 0);
        }
        // scores: valid keys are C cols 0-7; lanes<32 hold head rows 0-7
        if (lane < 32 && r < 8) {
            #pragma unroll
            for (int i = 0; i < 4; ++i)
                sc[(g * 4 + i) * PADK + k0 + r] = acc[i];
        }
    }
    __syncthreads();

    // ---- softmax: wave w owns heads 2w, 2w+1 ----
    for (int hh = 0; hh < 2; ++hh) {
        const int h = wave * 2 + hh;
        float s0[6];
        #pragma unroll
        for (int j = 0; j < 6; ++j) {
            const int k = lane + 64 * j;
            s0[j] = (k < limit) ? sc[h * PADK + k] : -1e15f;
        }
        float mx = s0[0];
        #pragma unroll
        for (int j = 1; j < 6; ++j) mx = fmaxf(mx, s0[j]);
        #pragma unroll
        for (int m = 1; m < 64; m <<= 1) mx = fmaxf(mx, __shfl_xor(mx, m, 64));
        float p[6]; float sum = 0.f;
        #pragma unroll
        for (int j = 0; j < 6; ++j) {
            const int k = lane + 64 * j;
            p[j] = (k < limit) ? __expf(s0[j] - mx) : 0.f;
            sum += p[j];
        }
        #pragma unroll
        for (int m = 1; m < 64; m <<= 1) sum += __shfl_xor(sum, m, 64);
        const float inv = 1.0f / sum;
        #pragma unroll
        for (int j = 0; j < 6; ++j) sc[h * PADK + lane + 64 * j] = p[j] * inv;
    }
    __syncthreads();

    // ---- PV: thread t -> (h = t>>5, d = t&31) ----
    {
        const int h = t >> 5;
        const int d = t & 31;
        const float* vcol = Vb + (size_t)b * S_ * H_ + h * DH_ + d;
        const float* prow = &sc[h * PADK];
        float acc = 0.f;
        int k = 0;
        for (; k + 8 <= limit; k += 8) {
            float vv[8], pp[8];
            #pragma unroll
            for (int u = 0; u < 8; ++u) vv[u] = vcol[(size_t)(k + u) * H_];
            #pragma unroll
            for (int u = 0; u < 8; ++u) pp[u] = prow[k + u];
            #pragma unroll
            for (int u = 0; u < 8; ++u) acc += pp[u] * vv[u];
        }
        for (; k < limit; ++k) acc += prow[k] * vcol[(size_t)k * H_];
        out[rowQ * H_ + h * DH_ + d] = acc;
    }
}

extern "C" void kernel_launch(void* const* d_in, const int* in_sizes, int n_in,
                              void* d_out, int out_size, void* d_ws, size_t ws_size,
                              hipStream_t stream)
{
    const float* key   = (const float*)d_in[0];
    const float* query = (const float*)d_in[1];
    const float* value = (const float*)d_in[2];
    const float* rpe   = (const float*)d_in[3];
    const int* seq_len = (const int*)d_in[4];
    const int* lex_num = (const int*)d_in[5];
    const float* Wk = (const float*)d_in[6];
    const float* bk = (const float*)d_in[7];
    const float* Wq = (const float*)d_in[8];
    const float* bq = (const float*)d_in[9];
    const float* Wv = (const float*)d_in[10];
    const float* bv = (const float*)d_in[11];
    const float* Wr = (const float*)d_in[12];
    const float* br = (const float*)d_in[13];
    (void)bk; (void)br;

    const size_t NTOK = (size_t)B_ * S_;          // 1536
    float* w = (float*)d_ws;
    float* Qb = w;                                 // f32 [1536*256]
    float* Vb = Qb + NTOK * H_;                    // f32 [1536*256]
    _Float16* Kf = (_Float16*)(Vb + NTOK * H_);    // f16 [1536*256]
    _Float16* Af = Kf + NTOK * H_;                 // f16 [1536*8*256]

    proj_kernel<<<dim3(48, 4, 3), dim3(256), 0, stream>>>(
        query, key, value, Wq, bq, Wk, bk, Wv, bv, Qb, Kf, Vb);
    qw_kernel<<<dim3(96, 8), dim3(256), 0, stream>>>(Qb, Wr, Af);
    attn_kernel<<<dim3(1536), dim3(256), 0, stream>>>(
        rpe, Af, Kf, Qb, Vb, seq_len, lex_num, (float*)d_out);
}

// Round 9
// 148.879 us; speedup vs baseline: 1.6810x; 1.6810x over previous
//
#include <hip/hip_runtime.h>
#include <hip/hip_bf16.h>
#include <stdint.h>

#define S_  384
#define H_  256
#define NH_ 8
#define DH_ 32
#define B_  4
#define PADK 385

typedef _Float16 f16x8 __attribute__((ext_vector_type(8)));
typedef _Float16 f16x4 __attribute__((ext_vector_type(4)));
typedef float    f32x4 __attribute__((ext_vector_type(4)));

// ---------------- Kernel P: fused QKV projections ----------------
// z==0 -> Qb (f32), z==1 -> Kf (f16), z==2 -> Vb (f32)
__global__ __launch_bounds__(256) void proj_kernel(
    const float* __restrict__ query, const float* __restrict__ key, const float* __restrict__ value,
    const float* __restrict__ Wq, const float* __restrict__ bq,
    const float* __restrict__ Wk, const float* __restrict__ bk,
    const float* __restrict__ Wv, const float* __restrict__ bv,
    float* __restrict__ Qb, _Float16* __restrict__ Kf, float* __restrict__ Vb)
{
    __shared__ __align__(16) float As[32][36];
    __shared__ __align__(16) float Bs[32][68];
    const int t = threadIdx.x;
    const int m0g = blockIdx.x * 32;
    const int n0g = blockIdx.y * 64;
    const int z = blockIdx.z;
    const float* X    = (z == 0) ? query : (z == 1 ? key : value);
    const float* W    = (z == 0) ? Wq    : (z == 1 ? Wk  : Wv);
    const float* bias = (z == 0) ? bq    : (z == 1 ? bk  : bv);

    const int tn = (t & 15) * 4;
    const int tm = (t >> 4) * 2;
    float acc0[4] = {0.f,0.f,0.f,0.f};
    float acc1[4] = {0.f,0.f,0.f,0.f};

    const int ar = t >> 3, ac4 = (t & 7) * 4;
    const int brr = t >> 4, bc4 = (t & 15) * 4;

    for (int kt = 0; kt < 8; ++kt) {
        const int k0 = kt * 32;
        float4 av  = *(const float4*)&X[(size_t)(m0g + ar) * H_ + k0 + ac4];
        float4 bv0 = *(const float4*)&W[(size_t)(k0 + brr)      * H_ + n0g + bc4];
        float4 bv1 = *(const float4*)&W[(size_t)(k0 + brr + 16) * H_ + n0g + bc4];
        *(float4*)&As[ar][ac4] = av;
        *(float4*)&Bs[brr][bc4] = bv0;
        *(float4*)&Bs[brr + 16][bc4] = bv1;
        __syncthreads();
        #pragma unroll
        for (int c = 0; c < 32; ++c) {
            const float a0 = As[tm][c], a1 = As[tm + 1][c];
            const float4 b4 = *(const float4*)&Bs[c][tn];
            acc0[0] += a0 * b4.x; acc0[1] += a0 * b4.y; acc0[2] += a0 * b4.z; acc0[3] += a0 * b4.w;
            acc1[0] += a1 * b4.x; acc1[1] += a1 * b4.y; acc1[2] += a1 * b4.z; acc1[3] += a1 * b4.w;
        }
        __syncthreads();
    }
    const float4 bi = *(const float4*)&bias[n0g + tn];
    float4 o0 = make_float4(acc0[0] + bi.x, acc0[1] + bi.y, acc0[2] + bi.z, acc0[3] + bi.w);
    float4 o1 = make_float4(acc1[0] + bi.x, acc1[1] + bi.y, acc1[2] + bi.z, acc1[3] + bi.w);
    if (z == 1) {
        f16x4 h0 = { (_Float16)o0.x, (_Float16)o0.y, (_Float16)o0.z, (_Float16)o0.w };
        f16x4 h1 = { (_Float16)o1.x, (_Float16)o1.y, (_Float16)o1.z, (_Float16)o1.w };
        *(f16x4*)&Kf[(size_t)(m0g + tm)     * H_ + n0g + tn] = h0;
        *(f16x4*)&Kf[(size_t)(m0g + tm + 1) * H_ + n0g + tn] = h1;
    } else {
        float* Out = (z == 0) ? Qb : Vb;
        *(float4*)&Out[(size_t)(m0g + tm)     * H_ + n0g + tn] = o0;
        *(float4*)&Out[(size_t)(m0g + tm + 1) * H_ + n0g + tn] = o1;
    }
}

// ---------------- Kernel QW: build A matrix per (b,q) (champion 512-wide layout) ----
// A[rowQ][h][0:256]   = f16(qW[h,e]) = f16(sum_d Q[rowQ,h*32+d] * Wr[e,h*32+d])
// A[rowQ][h][256:512] = (e>>5==h) ? f16(Q[rowQ,e]) : 0
__global__ __launch_bounds__(256) void qw_kernel(
    const float* __restrict__ Qb, const float* __restrict__ Wr,
    _Float16* __restrict__ Af)
{
    __shared__ __align__(16) float Qs[16][36];
    const int t = threadIdx.x;                // e index
    const int m0 = blockIdx.x * 16;
    const int h = blockIdx.y;

    float4 wr4[8];
    #pragma unroll
    for (int j = 0; j < 8; ++j)
        wr4[j] = *(const float4*)&Wr[(size_t)t * H_ + h * DH_ + j * 4];

    if (t < 128) {
        const int r = t >> 3, d4 = (t & 7) * 4;
        *(float4*)&Qs[r][d4] = *(const float4*)&Qb[(size_t)(m0 + r) * H_ + h * DH_ + d4];
    }
    __syncthreads();

    const bool own = ((t >> 5) == h);
    #pragma unroll 4
    for (int r = 0; r < 16; ++r) {
        float acc = 0.f;
        #pragma unroll
        for (int j = 0; j < 8; ++j) {
            const float4 qv = *(const float4*)&Qs[r][j * 4];
            acc += qv.x * wr4[j].x + qv.y * wr4[j].y + qv.z * wr4[j].z + qv.w * wr4[j].w;
        }
        _Float16* arow = Af + ((size_t)(m0 + r) * NH_ + h) * 512;
        arow[t] = (_Float16)acc;
        arow[256 + t] = own ? (_Float16)Qs[r][t & 31] : (_Float16)0.0f;
    }
}

// ---------------- Kernel B: MFMA scores with async DMA f32 staging ----------------
// One WG per (b,q); 4 waves; wave w owns 16-key tiles kt = w, w+4, ...
// Per tile: 16x global_load_lds (1KB rows, rotate-by-row source swizzle) ->
// vmcnt(0) -> per j-step {2x ds_read_b128 + 4x cvt_pkrtz + MFMA} -> 8 K-MFMA.
__global__ __launch_bounds__(256) void attn_kernel(
    const float* __restrict__ rpe, const _Float16* __restrict__ Af,
    const _Float16* __restrict__ Kf, const float* __restrict__ Vb,
    const int* __restrict__ seq_len, const int* __restrict__ lex_num,
    float* __restrict__ out)
{
    __shared__ float sc[NH_ * PADK];
    __shared__ __align__(16) float stgf[4][16][256];   // 64 KB f32 staging
    const int blk = blockIdx.x;
    const int b = blk / S_;
    const int q = blk - b * S_;
    const int t = threadIdx.x;
    const int lane = t & 63;
    const int wave = t >> 6;
    int limit = seq_len[b] + lex_num[b];
    limit = limit < 0 ? 0 : (limit > S_ ? S_ : limit);
    const size_t rowQ = (size_t)(b * S_ + q);

    if (limit == 0) {
        float acc = 0.f;
        const float* vb = Vb + (size_t)b * S_ * H_ + t;
        for (int k = 0; k < S_; ++k) acc += vb[(size_t)k * H_];
        out[rowQ * H_ + t] = acc * (1.0f / S_);
        return;
    }

    const int r = lane & 15;     // fragment row (key within tile / A row)
    const int g = lane >> 4;     // contraction k-group

    // A fragments for all 16 contraction steps (64 VGPR); rows r>=8 -> zero (C rows 8-15 unused)
    f16x8 afrag[16];
    {
        const _Float16* Arow = Af + rowQ * (NH_ * 512) + (size_t)r * 512;
        if (r < NH_) {
            #pragma unroll
            for (int j = 0; j < 16; ++j)
                afrag[j] = *(const f16x8*)(Arow + j * 32 + g * 8);
        } else {
            #pragma unroll
            for (int j = 0; j < 16; ++j)
                afrag[j] = (f16x8){};
        }
    }

    char* myl = (char*)&stgf[wave][0][0];
    const char* rpe_slab = (const char*)(rpe + rowQ * (size_t)S_ * H_);
    const int ntiles = (limit + 15) >> 4;

    // per-row DMA source byte offsets within the q-slab (rotate-by-row chunk swizzle)
    int off[16];
    #pragma unroll
    for (int rr = 0; rr < 16; ++rr)
        off[rr] = (wave * 16 + rr) * 1024 + (((lane & ~7) | ((lane - rr) & 7)) << 4);

    // read-side swizzled chunk offsets (lane constants)
    const int c0 = (((g * 2)     + r) & 7) * 16;
    const int c1 = (((g * 2) + 1 + r) & 7) * 16;
    const char* mrow = myl + r * 1024;

    for (int kt = wave; kt < ntiles; kt += 4) {
        const int k0 = kt * 16;
        // issue 16 row-DMAs (1KB each) straight into LDS
        #pragma unroll
        for (int rr = 0; rr < 16; ++rr) {
            __builtin_amdgcn_global_load_lds(
                (const __attribute__((address_space(1))) uint32_t*)(rpe_slab + off[rr]),
                (__attribute__((address_space(3))) uint32_t*)(myl + rr * 1024),
                16, 0, 0);
            off[rr] += 65536;   // wave strides 4 tiles = 64 rows
        }
        asm volatile("s_waitcnt vmcnt(0)" ::: "memory");

        f32x4 acc = {};
        #pragma unroll
        for (int j = 0; j < 8; ++j) {
            const float4 a  = *(const float4*)(mrow + j * 128 + c0);
            const float4 a2 = *(const float4*)(mrow + j * 128 + c1);
            union { decltype(__builtin_amdgcn_cvt_pkrtz(0.f, 0.f)) h2[4]; f16x8 h8; } u;
            u.h2[0] = __builtin_amdgcn_cvt_pkrtz(a.x,  a.y);
            u.h2[1] = __builtin_amdgcn_cvt_pkrtz(a.z,  a.w);
            u.h2[2] = __builtin_amdgcn_cvt_pkrtz(a2.x, a2.y);
            u.h2[3] = __builtin_amdgcn_cvt_pkrtz(a2.z, a2.w);
            acc = __builtin_amdgcn_mfma_f32_16x16x32_f16(afrag[j], u.h8, acc, 0, 0, 0);
        }
        const _Float16* krow = Kf + ((size_t)(b * S_ + k0 + r)) * H_ + g * 8;
        #pragma unroll
        for (int j = 0; j < 8; ++j) {
            const f16x8 kf = *(const f16x8*)(krow + j * 32);
            acc = __builtin_amdgcn_mfma_f32_16x16x32_f16(afrag[8 + j], kf, acc, 0, 0, 0);
        }
        // scores: lanes 0..31 hold heads 0..7 (C: col=lane&15, row=g*4+i)
        if (lane < 32) {
            #pragma unroll
            for (int i = 0; i < 4; ++i)
                sc[(g * 4 + i) * PADK + k0 + r] = acc[i];
        }
    }
    __syncthreads();

    // ---- softmax: wave w owns heads 2w, 2w+1 ----
    for (int hh = 0; hh < 2; ++hh) {
        const int h = wave * 2 + hh;
        float s0[6];
        #pragma unroll
        for (int j = 0; j < 6; ++j) {
            const int k = lane + 64 * j;
            s0[j] = (k < limit) ? sc[h * PADK + k] : -1e15f;
        }
        float mx = s0[0];
        #pragma unroll
        for (int j = 1; j < 6; ++j) mx = fmaxf(mx, s0[j]);
        #pragma unroll
        for (int m = 1; m < 64; m <<= 1) mx = fmaxf(mx, __shfl_xor(mx, m, 64));
        float p[6]; float sum = 0.f;
        #pragma unroll
        for (int j = 0; j < 6; ++j) {
            const int k = lane + 64 * j;
            p[j] = (k < limit) ? __expf(s0[j] - mx) : 0.f;
            sum += p[j];
        }
        #pragma unroll
        for (int m = 1; m < 64; m <<= 1) sum += __shfl_xor(sum, m, 64);
        const float inv = 1.0f / sum;
        #pragma unroll
        for (int j = 0; j < 6; ++j) sc[h * PADK + lane + 64 * j] = p[j] * inv;
    }
    __syncthreads();

    // ---- PV: thread t -> (h = t>>5, d = t&31) ----
    {
        const int h = t >> 5;
        const int d = t & 31;
        const float* vcol = Vb + (size_t)b * S_ * H_ + h * DH_ + d;
        const float* prow = &sc[h * PADK];
        float acc = 0.f;
        int k = 0;
        for (; k + 8 <= limit; k += 8) {
            float vv[8], pp[8];
            #pragma unroll
            for (int u = 0; u < 8; ++u) vv[u] = vcol[(size_t)(k + u) * H_];
            #pragma unroll
            for (int u = 0; u < 8; ++u) pp[u] = prow[k + u];
            #pragma unroll
            for (int u = 0; u < 8; ++u) acc += pp[u] * vv[u];
        }
        for (; k < limit; ++k) acc += prow[k] * vcol[(size_t)k * H_];
        out[rowQ * H_ + h * DH_ + d] = acc;
    }
}

extern "C" void kernel_launch(void* const* d_in, const int* in_sizes, int n_in,
                              void* d_out, int out_size, void* d_ws, size_t ws_size,
                              hipStream_t stream)
{
    const float* key   = (const float*)d_in[0];
    const float* query = (const float*)d_in[1];
    const float* value = (const float*)d_in[2];
    const float* rpe   = (const float*)d_in[3];
    const int* seq_len = (const int*)d_in[4];
    const int* lex_num = (const int*)d_in[5];
    const float* Wk = (const float*)d_in[6];
    const float* bk = (const float*)d_in[7];
    const float* Wq = (const float*)d_in[8];
    const float* bq = (const float*)d_in[9];
    const float* Wv = (const float*)d_in[10];
    const float* bv = (const float*)d_in[11];
    const float* Wr = (const float*)d_in[12];
    const float* br = (const float*)d_in[13];
    (void)bk; (void)br;

    const size_t NTOK = (size_t)B_ * S_;          // 1536
    float* w = (float*)d_ws;
    float* Qb = w;                                 // f32 [1536*256]
    float* Vb = Qb + NTOK * H_;                    // f32 [1536*256]
    _Float16* Kf = (_Float16*)(Vb + NTOK * H_);    // f16 [1536*256]
    _Float16* Af = Kf + NTOK * H_;                 // f16 [1536*8*512]

    proj_kernel<<<dim3(48, 4, 3), dim3(256), 0, stream>>>(
        query, key, value, Wq, bq, Wk, bk, Wv, bv, Qb, Kf, Vb);
    qw_kernel<<<dim3(96, 8), dim3(256), 0, stream>>>(Qb, Wr, Af);
    attn_kernel<<<dim3(1536), dim3(256), 0, stream>>>(
        rpe, Af, Kf, Vb, seq_len, lex_num, (float*)d_out);
}

// Round 10
// 138.904 us; speedup vs baseline: 1.8018x; 1.0718x over previous
//
#include <hip/hip_runtime.h>
#include <hip/hip_bf16.h>

#define S_  384
#define H_  256
#define NH_ 8
#define DH_ 32
#define B_  4
#define PADK 385

typedef _Float16 f16x8 __attribute__((ext_vector_type(8)));
typedef _Float16 f16x4 __attribute__((ext_vector_type(4)));
typedef float    f32x4 __attribute__((ext_vector_type(4)));

// ---------------- Kernel P: fused QKV projections ----------------
// z==0 -> Qb (f32), z==1 -> Kf (f16), z==2 -> Vb (f32)
__global__ __launch_bounds__(256) void proj_kernel(
    const float* __restrict__ query, const float* __restrict__ key, const float* __restrict__ value,
    const float* __restrict__ Wq, const float* __restrict__ bq,
    const float* __restrict__ Wk, const float* __restrict__ bk,
    const float* __restrict__ Wv, const float* __restrict__ bv,
    float* __restrict__ Qb, _Float16* __restrict__ Kf, float* __restrict__ Vb)
{
    __shared__ __align__(16) float As[32][36];
    __shared__ __align__(16) float Bs[32][68];
    const int t = threadIdx.x;
    const int m0g = blockIdx.x * 32;
    const int n0g = blockIdx.y * 64;
    const int z = blockIdx.z;
    const float* X    = (z == 0) ? query : (z == 1 ? key : value);
    const float* W    = (z == 0) ? Wq    : (z == 1 ? Wk  : Wv);
    const float* bias = (z == 0) ? bq    : (z == 1 ? bk  : bv);

    const int tn = (t & 15) * 4;
    const int tm = (t >> 4) * 2;
    float acc0[4] = {0.f,0.f,0.f,0.f};
    float acc1[4] = {0.f,0.f,0.f,0.f};

    const int ar = t >> 3, ac4 = (t & 7) * 4;
    const int brr = t >> 4, bc4 = (t & 15) * 4;

    for (int kt = 0; kt < 8; ++kt) {
        const int k0 = kt * 32;
        float4 av  = *(const float4*)&X[(size_t)(m0g + ar) * H_ + k0 + ac4];
        float4 bv0 = *(const float4*)&W[(size_t)(k0 + brr)      * H_ + n0g + bc4];
        float4 bv1 = *(const float4*)&W[(size_t)(k0 + brr + 16) * H_ + n0g + bc4];
        *(float4*)&As[ar][ac4] = av;
        *(float4*)&Bs[brr][bc4] = bv0;
        *(float4*)&Bs[brr + 16][bc4] = bv1;
        __syncthreads();
        #pragma unroll
        for (int c = 0; c < 32; ++c) {
            const float a0 = As[tm][c], a1 = As[tm + 1][c];
            const float4 b4 = *(const float4*)&Bs[c][tn];
            acc0[0] += a0 * b4.x; acc0[1] += a0 * b4.y; acc0[2] += a0 * b4.z; acc0[3] += a0 * b4.w;
            acc1[0] += a1 * b4.x; acc1[1] += a1 * b4.y; acc1[2] += a1 * b4.z; acc1[3] += a1 * b4.w;
        }
        __syncthreads();
    }
    const float4 bi = *(const float4*)&bias[n0g + tn];
    float4 o0 = make_float4(acc0[0] + bi.x, acc0[1] + bi.y, acc0[2] + bi.z, acc0[3] + bi.w);
    float4 o1 = make_float4(acc1[0] + bi.x, acc1[1] + bi.y, acc1[2] + bi.z, acc1[3] + bi.w);
    if (z == 1) {
        f16x4 h0 = { (_Float16)o0.x, (_Float16)o0.y, (_Float16)o0.z, (_Float16)o0.w };
        f16x4 h1 = { (_Float16)o1.x, (_Float16)o1.y, (_Float16)o1.z, (_Float16)o1.w };
        *(f16x4*)&Kf[(size_t)(m0g + tm)     * H_ + n0g + tn] = h0;
        *(f16x4*)&Kf[(size_t)(m0g + tm + 1) * H_ + n0g + tn] = h1;
    } else {
        float* Out = (z == 0) ? Qb : Vb;
        *(float4*)&Out[(size_t)(m0g + tm)     * H_ + n0g + tn] = o0;
        *(float4*)&Out[(size_t)(m0g + tm + 1) * H_ + n0g + tn] = o1;
    }
}

// ---------------- Kernel QW: build A matrix per (b,q) ----------------
// A[rowQ][h][0:256]   = f16(qW[h,e]) = f16(sum_d Q[rowQ,h*32+d] * Wr[e,h*32+d])
// A[rowQ][h][256:512] = (e>>5==h) ? f16(Q[rowQ,e]) : 0
__global__ __launch_bounds__(256) void qw_kernel(
    const float* __restrict__ Qb, const float* __restrict__ Wr,
    _Float16* __restrict__ Af)
{
    __shared__ __align__(16) float Qs[16][36];
    const int t = threadIdx.x;                // e index
    const int m0 = blockIdx.x * 16;
    const int h = blockIdx.y;

    float4 wr4[8];
    #pragma unroll
    for (int j = 0; j < 8; ++j)
        wr4[j] = *(const float4*)&Wr[(size_t)t * H_ + h * DH_ + j * 4];

    if (t < 128) {
        const int r = t >> 3, d4 = (t & 7) * 4;
        *(float4*)&Qs[r][d4] = *(const float4*)&Qb[(size_t)(m0 + r) * H_ + h * DH_ + d4];
    }
    __syncthreads();

    const bool own = ((t >> 5) == h);
    #pragma unroll 4
    for (int r = 0; r < 16; ++r) {
        float acc = 0.f;
        #pragma unroll
        for (int j = 0; j < 8; ++j) {
            const float4 qv = *(const float4*)&Qs[r][j * 4];
            acc += qv.x * wr4[j].x + qv.y * wr4[j].y + qv.z * wr4[j].z + qv.w * wr4[j].w;
        }
        _Float16* arow = Af + ((size_t)(m0 + r) * NH_ + h) * 512;
        arow[t] = (_Float16)acc;
        arow[256 + t] = own ? (_Float16)Qs[r][t & 31] : (_Float16)0.0f;
    }
}

// ---------------- Kernel B: MFMA scores + mask + softmax + PV ----------------
// Champion structure (R3): one WG per (b,q); 4 waves; wave w owns key-tiles
// kt = w, w+4, ... Per tile: stage 16 rpe rows f32->f16 into wave-private
// swizzled LDS, then 16x mfma_f32_16x16x32_f16.
// ONE change vs champion: the 16-deep MFMA accumulation chain is split into
// 4 independent accumulators (chain depth 4), summed at the end.
__global__ __launch_bounds__(256) void attn_kernel(
    const float* __restrict__ rpe, const _Float16* __restrict__ Af,
    const _Float16* __restrict__ Kf, const float* __restrict__ Vb,
    const int* __restrict__ seq_len, const int* __restrict__ lex_num,
    float* __restrict__ out)
{
    __shared__ float sc[NH_ * PADK];
    __shared__ __align__(16) _Float16 stg[4][16][256];
    const int blk = blockIdx.x;
    const int b = blk / S_;
    const int q = blk - b * S_;
    const int t = threadIdx.x;
    const int lane = t & 63;
    const int wave = t >> 6;
    int limit = seq_len[b] + lex_num[b];
    limit = limit < 0 ? 0 : (limit > S_ ? S_ : limit);
    const size_t rowQ = (size_t)(b * S_ + q);

    if (limit == 0) {
        float acc = 0.f;
        const float* vb = Vb + (size_t)b * S_ * H_ + t;
        for (int k = 0; k < S_; ++k) acc += vb[(size_t)k * H_];
        out[rowQ * H_ + t] = acc * (1.0f / S_);
        return;
    }

    const int r = lane & 15;     // fragment row: A-row (head) / key within tile
    const int g = lane >> 4;     // k-group within fragment

    // ---- hoist A-fragments for all 16 contraction steps (64 VGPR) ----
    f16x8 afrag[16];
    {
        const _Float16* Arow = Af + rowQ * (NH_ * 512) + (size_t)r * 512;
        if (r < NH_) {
            #pragma unroll
            for (int j = 0; j < 16; ++j)
                afrag[j] = *(const f16x8*)(Arow + j * 32 + g * 8);
        } else {
            #pragma unroll
            for (int j = 0; j < 16; ++j)
                afrag[j] = (f16x8){};
        }
    }

    char* myl = (char*)&stg[wave][0][0];
    const int swzr = (r & 7) << 4;
    const float* rpe_base = rpe + rowQ * (size_t)S_ * H_;
    const int ntiles = (limit + 15) >> 4;

    for (int kt = wave; kt < ntiles; kt += 4) {
        const int k0 = kt * 16;
        const float* gsrc = rpe_base + (size_t)k0 * H_;
        // ---- stage 16 rows (f32 -> f16, swizzled) ----
        #pragma unroll
        for (int half = 0; half < 2; ++half) {
            float4 v[8];
            #pragma unroll
            for (int rr = 0; rr < 8; ++rr)
                v[rr] = *(const float4*)&gsrc[(size_t)(half * 8 + rr) * H_ + lane * 4];
            #pragma unroll
            for (int rr = 0; rr < 8; ++rr) {
                const int row = half * 8 + rr;
                f16x4 hv = { (_Float16)v[rr].x, (_Float16)v[rr].y,
                             (_Float16)v[rr].z, (_Float16)v[rr].w };
                *(f16x4*)(myl + row * 512 + ((lane * 8) ^ ((row & 7) << 4))) = hv;
            }
        }
        // ---- MFMA: 8 rpe steps (LDS) + 8 K steps, 4 independent acc chains ----
        f32x4 accA = {}, accB = {}, accC = {}, accD = {};
        #pragma unroll
        for (int j = 0; j < 8; j += 2) {
            f16x8 bf0 = *(const f16x8*)(myl + r * 512 + (((j    ) * 64 + g * 16) ^ swzr));
            f16x8 bf1 = *(const f16x8*)(myl + r * 512 + (((j + 1) * 64 + g * 16) ^ swzr));
            accA = __builtin_amdgcn_mfma_f32_16x16x32_f16(afrag[j],     bf0, accA, 0, 0, 0);
            accB = __builtin_amdgcn_mfma_f32_16x16x32_f16(afrag[j + 1], bf1, accB, 0, 0, 0);
        }
        const _Float16* krow = Kf + ((size_t)(b * S_ + k0 + r)) * H_ + g * 8;
        #pragma unroll
        for (int j = 0; j < 8; j += 2) {
            const f16x8 kf0 = *(const f16x8*)(krow + (j    ) * 32);
            const f16x8 kf1 = *(const f16x8*)(krow + (j + 1) * 32);
            accC = __builtin_amdgcn_mfma_f32_16x16x32_f16(afrag[8 + j],     kf0, accC, 0, 0, 0);
            accD = __builtin_amdgcn_mfma_f32_16x16x32_f16(afrag[8 + j + 1], kf1, accD, 0, 0, 0);
        }
        const f32x4 acc = (accA + accB) + (accC + accD);
        // ---- write scores: lanes 0..31 hold heads 0..7 (C: col=lane&15, row=g*4+i) ----
        if (lane < 32) {
            #pragma unroll
            for (int i = 0; i < 4; ++i)
                sc[(g * 4 + i) * PADK + k0 + r] = acc[i];
        }
    }
    __syncthreads();

    // ---- softmax: wave w owns heads 2w, 2w+1 ----
    for (int hh = 0; hh < 2; ++hh) {
        const int h = wave * 2 + hh;
        float s0[6];
        #pragma unroll
        for (int j = 0; j < 6; ++j) {
            const int k = lane + 64 * j;
            s0[j] = (k < limit) ? sc[h * PADK + k] : -1e15f;
        }
        float mx = s0[0];
        #pragma unroll
        for (int j = 1; j < 6; ++j) mx = fmaxf(mx, s0[j]);
        #pragma unroll
        for (int m = 1; m < 64; m <<= 1) mx = fmaxf(mx, __shfl_xor(mx, m, 64));
        float p[6]; float sum = 0.f;
        #pragma unroll
        for (int j = 0; j < 6; ++j) {
            const int k = lane + 64 * j;
            p[j] = (k < limit) ? __expf(s0[j] - mx) : 0.f;
            sum += p[j];
        }
        #pragma unroll
        for (int m = 1; m < 64; m <<= 1) sum += __shfl_xor(sum, m, 64);
        const float inv = 1.0f / sum;
        #pragma unroll
        for (int j = 0; j < 6; ++j) sc[h * PADK + lane + 64 * j] = p[j] * inv;
    }
    __syncthreads();

    // ---- PV: thread t -> (h = t>>5, d = t&31) ----
    {
        const int h = t >> 5;
        const int d = t & 31;
        const float* vcol = Vb + (size_t)b * S_ * H_ + h * DH_ + d;
        const float* prow = &sc[h * PADK];
        float acc = 0.f;
        int k = 0;
        for (; k + 8 <= limit; k += 8) {
            float vv[8], pp[8];
            #pragma unroll
            for (int u = 0; u < 8; ++u) vv[u] = vcol[(size_t)(k + u) * H_];
            #pragma unroll
            for (int u = 0; u < 8; ++u) pp[u] = prow[k + u];
            #pragma unroll
            for (int u = 0; u < 8; ++u) acc += pp[u] * vv[u];
        }
        for (; k < limit; ++k) acc += prow[k] * vcol[(size_t)k * H_];
        out[rowQ * H_ + h * DH_ + d] = acc;
    }
}

extern "C" void kernel_launch(void* const* d_in, const int* in_sizes, int n_in,
                              void* d_out, int out_size, void* d_ws, size_t ws_size,
                              hipStream_t stream)
{
    const float* key   = (const float*)d_in[0];
    const float* query = (const float*)d_in[1];
    const float* value = (const float*)d_in[2];
    const float* rpe   = (const float*)d_in[3];
    const int* seq_len = (const int*)d_in[4];
    const int* lex_num = (const int*)d_in[5];
    const float* Wk = (const float*)d_in[6];
    const float* bk = (const float*)d_in[7];
    const float* Wq = (const float*)d_in[8];
    const float* bq = (const float*)d_in[9];
    const float* Wv = (const float*)d_in[10];
    const float* bv = (const float*)d_in[11];
    const float* Wr = (const float*)d_in[12];
    const float* br = (const float*)d_in[13];
    (void)bk; (void)br;

    const size_t NTOK = (size_t)B_ * S_;          // 1536
    float* w = (float*)d_ws;
    float* Qb = w;                                 // f32 [1536*256]
    float* Vb = Qb + NTOK * H_;                    // f32 [1536*256]
    _Float16* Kf = (_Float16*)(Vb + NTOK * H_);    // f16 [1536*256]
    _Float16* Af = Kf + NTOK * H_;                 // f16 [1536*8*512]

    proj_kernel<<<dim3(48, 4, 3), dim3(256), 0, stream>>>(
        query, key, value, Wq, bq, Wk, bk, Wv, bv, Qb, Kf, Vb);
    qw_kernel<<<dim3(96, 8), dim3(256), 0, stream>>>(Qb, Wr, Af);
    attn_kernel<<<dim3(1536), dim3(256), 0, stream>>>(
        rpe, Af, Kf, Vb, seq_len, lex_num, (float*)d_out);
}